// Round 27
// baseline (6791.998 us; speedup 1.0000x reference)
//
#include <hip/hip_runtime.h>

#define NPTS   262144
#define DIM    128
#define DIM4   32
#define KC     102
#define NITERS 10
#define NBLK_H 512
#define CHK    512

// Reference model (identified r18-r23, bit-exact PASS r21/r23/r24/r25/r26):
//   x_sq/csq: numpy pairwise 8-acc tree, materialized squares
//   dot:      2-acc even/odd k-split FMA chains, D = fl(t0+t1)
//   d2:       fl(x_sq - 2D) + csq (two roundings); first-min argmin
//   segsum:   ascending-p sequential f32 adds per (cluster,dim); f32 divide
//   where:    empty cluster keeps old centroid

// ws layout (bytes)
#define WS_CA    0
#define WS_CB    53248
#define WS_CSQ   106496
#define WS_CNT   107520
#define WS_CBASE 108544
#define WS_H     109568
#define WS_OFFS  318464
#define WS_PT    527360
#define WS_NEED  1575936

__global__ void k_fill(int* __restrict__ p, int n, int v)
{
    const int i = blockIdx.x * 256 + threadIdx.x;
    if (i < n) p[i] = v;
}

// numpy pairwise tree, n=128 (8 accumulators, materialized squares)
__device__ __forceinline__ float np_sumsq128(const float* a)
{
#pragma clang fp contract(off)
    float r[8];
    #pragma unroll
    for (int t = 0; t < 8; ++t) { const float v = a[t]; r[t] = v * v; }
    #pragma unroll
    for (int i = 8; i < 128; i += 8) {
        #pragma unroll
        for (int t = 0; t < 8; ++t) { const float v = a[i + t]; r[t] += v * v; }
    }
    return ((r[0] + r[1]) + (r[2] + r[3])) + ((r[4] + r[5]) + (r[6] + r[7]));
}

__device__ __forceinline__ float xr_get(const float4* xr, int i)
{
    const float4 v = xr[i >> 2];
    const int c = i & 3;
    return c == 0 ? v.x : c == 1 ? v.y : c == 2 ? v.z : v.w;
}

__device__ __forceinline__ float np_sumsq128_reg(const float4* xr)
{
#pragma clang fp contract(off)
    float r[8];
    #pragma unroll
    for (int t = 0; t < 8; ++t) { const float v = xr_get(xr, t); r[t] = v * v; }
    #pragma unroll
    for (int i = 8; i < 128; i += 8) {
        #pragma unroll
        for (int t = 0; t < 8; ++t) { const float v = xr_get(xr, i + t); r[t] += v * v; }
    }
    return ((r[0] + r[1]) + (r[2] + r[3])) + ((r[4] + r[5]) + (r[6] + r[7]));
}

__global__ __launch_bounds__(128)
void k_initc(const float* __restrict__ x, float* __restrict__ c, float* __restrict__ csq)
{
    __shared__ float row[DIM];
    const int j = blockIdx.x, d = threadIdx.x;
    const float v = x[(size_t)j * DIM + d];
    c[j * DIM + d] = v;
    row[d] = v;
    __syncthreads();
    if (d == 0) csq[j] = np_sumsq128(row);
}

// fast f32 4-chain scan + exact-reference rescue
__global__ __launch_bounds__(256, 2)
void k_assign(const float* __restrict__ x, const float* __restrict__ c,
              const float* __restrict__ csq, int* __restrict__ labels)
{
    __shared__ float4 cl[KC * DIM4];
    __shared__ float  sj[KC];
    for (int i = threadIdx.x; i < KC * DIM4; i += 256)
        cl[i] = reinterpret_cast<const float4*>(c)[i];
    for (int i = threadIdx.x; i < KC; i += 256) sj[i] = csq[i];
    __syncthreads();

    const int p = blockIdx.x * 256 + threadIdx.x;
    const float4* xp = reinterpret_cast<const float4*>(x) + (size_t)p * DIM4;
    float4 xr[DIM4];
    #pragma unroll
    for (int q = 0; q < DIM4; ++q) xr[q] = xp[q];

    float best1 = 3.4e38f, best2 = 3.4e38f;
    int bi = 0;
    for (int j = 0; j < KC; ++j) {
        const float4* cj = &cl[j * DIM4];
        float a0 = 0.f, a1 = 0.f, a2 = 0.f, a3 = 0.f;
        #pragma unroll
        for (int q = 0; q < DIM4; ++q) {
            const float4 cv = cj[q];
            a0 = __builtin_fmaf(xr[q].x, cv.x, a0);
            a1 = __builtin_fmaf(xr[q].y, cv.y, a1);
            a2 = __builtin_fmaf(xr[q].z, cv.z, a2);
            a3 = __builtin_fmaf(xr[q].w, cv.w, a3);
        }
        const float F = sj[j] - 2.0f * ((a0 + a1) + (a2 + a3));
        if (F < best1)      { best2 = best1; best1 = F; bi = j; }
        else if (F < best2) { best2 = F; }
    }

    int lab = bi;
    if (best2 - best1 < 0.02f) {
        const float Tp  = np_sumsq128_reg(xr);
        const float win = best1 + 0.02f;
        float bestE = 3.4e38f;
        int bj = bi;
        for (int j = 0; j < KC; ++j) {
            const float4* cj = &cl[j * DIM4];
            float a0 = 0.f, a1 = 0.f, a2 = 0.f, a3 = 0.f;
            #pragma unroll
            for (int q = 0; q < DIM4; ++q) {
                const float4 cv = cj[q];
                a0 = __builtin_fmaf(xr[q].x, cv.x, a0);
                a1 = __builtin_fmaf(xr[q].y, cv.y, a1);
                a2 = __builtin_fmaf(xr[q].z, cv.z, a2);
                a3 = __builtin_fmaf(xr[q].w, cv.w, a3);
            }
            const float F = sj[j] - 2.0f * ((a0 + a1) + (a2 + a3));
            if (F <= win) {
                float t0 = 0.f, t1 = 0.f;
                #pragma unroll
                for (int q = 0; q < DIM4; ++q) {
                    const float4 cv = cj[q];
                    t0 = __builtin_fmaf(xr[q].x, cv.x, t0);
                    t1 = __builtin_fmaf(xr[q].y, cv.y, t1);
                    t0 = __builtin_fmaf(xr[q].z, cv.z, t0);
                    t1 = __builtin_fmaf(xr[q].w, cv.w, t1);
                }
                float E;
                {
#pragma clang fp contract(off)
                    const float D = t0 + t1;
                    const float u = Tp - 2.0f * D;
                    E = u + sj[j];
                }
                if (E < bestE) { bestE = E; bj = j; }
            }
        }
        lab = bj;
    }
    labels[p] = lab;
}

__global__ __launch_bounds__(256)
void k_hist(const int* __restrict__ labels, int* __restrict__ H)
{
    __shared__ int h[KC];
    for (int i = threadIdx.x; i < KC; i += 256) h[i] = 0;
    __syncthreads();
    const int b = blockIdx.x;
    #pragma unroll
    for (int u = 0; u < 2; ++u)
        atomicAdd(&h[labels[b * CHK + u * 256 + threadIdx.x]], 1);
    __syncthreads();
    for (int i = threadIdx.x; i < KC; i += 256) H[i * NBLK_H + b] = h[i];
}

__global__ __launch_bounds__(128)
void k_scan(const int* __restrict__ H, int* __restrict__ OFFS,
            int* __restrict__ counts, int* __restrict__ cbase)
{
    __shared__ int tot[KC];
    const int j = threadIdx.x;
    if (j < KC) {
        int run = 0;
        for (int b = 0; b < NBLK_H; ++b) { OFFS[j * NBLK_H + b] = run; run += H[j * NBLK_H + b]; }
        tot[j] = run;
    }
    __syncthreads();
    if (j == 0) {
        int base = 0;
        for (int jj = 0; jj < KC; ++jj) { cbase[jj] = base; counts[jj] = tot[jj]; base += tot[jj]; }
    }
}

// stable scatter: serial lane preserves ascending-p order within block
__global__ __launch_bounds__(64)
void k_scatter(const int* __restrict__ labels, const int* __restrict__ OFFS,
               const int* __restrict__ cbase, int* __restrict__ ptidx)
{
    __shared__ int lab[CHK];
    __shared__ int lrank[KC];
    __shared__ int soff[KC];
    const int b = blockIdx.x;
    for (int i = threadIdx.x; i < CHK; i += 64) lab[i] = labels[b * CHK + i];
    for (int i = threadIdx.x; i < KC; i += 64) { lrank[i] = 0; soff[i] = cbase[i] + OFFS[i * NBLK_H + b]; }
    __syncthreads();
    if (threadIdx.x == 0) {
        for (int i = 0; i < CHK; ++i) {
            const int l = lab[i];
            ptidx[soff[l] + lrank[l]++] = b * CHK + i;
        }
    }
}

// exact segment sums: ascending-p sequential f32 adds.
// 16-deep software pipeline in 32 NAMED scalars (cannot be stack-demoted),
// ping-pong batches; LDS-double-buffered index prefetch.
#define LOAD16(S, off)                                                          \
    S##0  = x[(size_t)sp[(off) + 0]  * DIM + d];                                \
    S##1  = x[(size_t)sp[(off) + 1]  * DIM + d];                                \
    S##2  = x[(size_t)sp[(off) + 2]  * DIM + d];                                \
    S##3  = x[(size_t)sp[(off) + 3]  * DIM + d];                                \
    S##4  = x[(size_t)sp[(off) + 4]  * DIM + d];                                \
    S##5  = x[(size_t)sp[(off) + 5]  * DIM + d];                                \
    S##6  = x[(size_t)sp[(off) + 6]  * DIM + d];                                \
    S##7  = x[(size_t)sp[(off) + 7]  * DIM + d];                                \
    S##8  = x[(size_t)sp[(off) + 8]  * DIM + d];                                \
    S##9  = x[(size_t)sp[(off) + 9]  * DIM + d];                                \
    S##10 = x[(size_t)sp[(off) + 10] * DIM + d];                                \
    S##11 = x[(size_t)sp[(off) + 11] * DIM + d];                                \
    S##12 = x[(size_t)sp[(off) + 12] * DIM + d];                                \
    S##13 = x[(size_t)sp[(off) + 13] * DIM + d];                                \
    S##14 = x[(size_t)sp[(off) + 14] * DIM + d];                                \
    S##15 = x[(size_t)sp[(off) + 15] * DIM + d]

#define SUM16(S)                                                                \
    s += S##0;  s += S##1;  s += S##2;  s += S##3;                              \
    s += S##4;  s += S##5;  s += S##6;  s += S##7;                              \
    s += S##8;  s += S##9;  s += S##10; s += S##11;                             \
    s += S##12; s += S##13; s += S##14; s += S##15

__global__ __launch_bounds__(128, 1)
void k_update(const float* __restrict__ x, const int* __restrict__ ptidx,
              const int* __restrict__ counts, const int* __restrict__ cbase,
              const float* __restrict__ cold, float* __restrict__ cnew,
              float* __restrict__ csq)
{
    __shared__ int   spt[2][CHK];
    __shared__ float row[DIM];
    const int j = blockIdx.x, d = threadIdx.x;
    const int n = counts[j], base = cbase[j];
    const int nchunks = (n + CHK - 1) / CHK;

    if (n > 0) {
        const int m0 = min(CHK, n);
        for (int i = d; i < m0; i += 128) spt[0][i] = ptidx[base + i];
    }
    __syncthreads();

    float s = 0.f;
    float a0,a1,a2,a3,a4,a5,a6,a7,a8,a9,a10,a11,a12,a13,a14,a15;
    float b0,b1,b2,b3,b4,b5,b6,b7,b8,b9,b10,b11,b12,b13,b14,b15;

    for (int cc = 0; cc < nchunks; ++cc) {
        const int c0 = cc * CHK;
        const int m  = min(CHK, n - c0);
        const int cb = cc & 1;
        const int* sp = spt[cb];

        // prefetch next index chunk into the other LDS buffer
        if (cc + 1 < nchunks) {
            const int c1 = (cc + 1) * CHK;
            const int m1 = min(CHK, n - c1);
            for (int i = d; i < m1; i += 128) spt[cb ^ 1][i] = ptidx[base + c1 + i];
        }

        const int nb = (m & ~15) >> 4;   // full batches of 16
        if (nb > 0) {
            LOAD16(a, 0);
            for (int k = 0; k < nb; ++k) {
                if ((k & 1) == 0) {
                    if (k + 1 < nb) { LOAD16(b, (k + 1) * 16); }
                    {
#pragma clang fp contract(off)
                        SUM16(a);
                    }
                } else {
                    if (k + 1 < nb) { LOAD16(a, (k + 1) * 16); }
                    {
#pragma clang fp contract(off)
                        SUM16(b);
                    }
                }
            }
        }
        {
#pragma clang fp contract(off)
            for (int t = nb * 16; t < m; ++t) s += x[(size_t)sp[t] * DIM + d];
        }
        __syncthreads();
    }

    const float v = (n > 0) ? (s / fmaxf((float)n, 1.0f)) : cold[j * DIM + d];
    cnew[j * DIM + d] = v;
    row[d] = v;
    __syncthreads();
    if (d == 0) csq[j] = np_sumsq128(row);
}

extern "C" void kernel_launch(void* const* d_in, const int* in_sizes, int n_in,
                              void* d_out, int out_size, void* d_ws, size_t ws_size,
                              hipStream_t stream)
{
    int* labels = (int*)d_out;

    const float* x = nullptr;
    for (int i = 0; i < n_in; ++i)
        if (in_sizes[i] == NPTS * DIM) { x = (const float*)d_in[i]; break; }
    if (!x)                        { k_fill<<<(NPTS+255)/256, 256, 0, stream>>>(labels, NPTS, 2000); return; }
    if (ws_size < (size_t)WS_NEED) { k_fill<<<(NPTS+255)/256, 256, 0, stream>>>(labels, NPTS, 3000); return; }

    char* w = (char*)d_ws;
    float* c_a    = (float*)(w + WS_CA);
    float* c_b    = (float*)(w + WS_CB);
    float* csq    = (float*)(w + WS_CSQ);
    int*   counts = (int*)  (w + WS_CNT);
    int*   cbase  = (int*)  (w + WS_CBASE);
    int*   H      = (int*)  (w + WS_H);
    int*   OFFS   = (int*)  (w + WS_OFFS);
    int*   ptidx  = (int*)  (w + WS_PT);

    k_initc<<<KC, 128, 0, stream>>>(x, c_a, csq);

    float* c_cur = c_a;
    float* c_nxt = c_b;
    for (int it = 0; it < NITERS; ++it) {
        k_assign<<<NPTS / 256, 256, 0, stream>>>(x, c_cur, csq, labels);
        if (it < NITERS - 1) {
            k_hist   <<<NBLK_H, 256, 0, stream>>>(labels, H);
            k_scan   <<<1, 128, 0, stream>>>(H, OFFS, counts, cbase);
            k_scatter<<<NBLK_H, 64, 0, stream>>>(labels, OFFS, cbase, ptidx);
            k_update <<<KC, 128, 0, stream>>>(x, ptidx, counts, cbase, c_cur, c_nxt, csq);
            float* tmp = c_cur; c_cur = c_nxt; c_nxt = tmp;
        }
    }
}